// Round 11
// baseline (86.065 us; speedup 1.0000x reference)
//
#include <hip/hip_runtime.h>
#include <math.h>

// Problem constants
#define M_ROWS   8192     // B*S
#define N_CODES  16384
#define D_DIM    32
#define NTHREADS 256

// Certification margin (R7/R8/R10: absmax 0 at this margin). See error budget
// in earlier rounds: certify iff dist-gap > 8.2e-5; 2e-4 = 2.4x cushion.
#define DELTA_MARGIN  2e-4f

// ===== cleanup parameters =====
#define NCHUNK       16
#define CHUNK_CODES  (N_CODES / NCHUNK)       // 1024
#define SCAN_SLOTS   256                       // row-slot stride in scan grid

typedef short bf16x8 __attribute__((ext_vector_type(8)));  // 8 bf16
typedef float f32x4  __attribute__((ext_vector_type(4)));

// round-to-nearest-even fp32 -> bf16 bits
__device__ inline unsigned short bf16_rne(float f) {
    unsigned u = __float_as_uint(f);
    unsigned r = u + 0x7FFFu + ((u >> 16) & 1u);
    return (unsigned short)(r >> 16);
}

__device__ inline void pack_pair(float f0, float f1, unsigned& hi, unsigned& lo) {
    unsigned short h0 = bf16_rne(f0), h1 = bf16_rne(f1);
    float r0 = f0 - __uint_as_float((unsigned)h0 << 16);
    float r1 = f1 - __uint_as_float((unsigned)h1 << 16);
    unsigned short l0 = bf16_rne(r0), l1 = bf16_rne(r1);
    hi = (unsigned)h0 | ((unsigned)h1 << 16);
    lo = (unsigned)l0 | ((unsigned)l1 << 16);
}

// ---------------------------------------------------------------------------
// Prep+pack v2 (float4-vectorized, fmaf order identical to validated chain):
//   blocks 0..63: cc[n] + codebook hi/lo bf16 pack
//   blocks 64..95: normalize z -> zn (d_out), zz, z hi/lo bf16 pack
// ---------------------------------------------------------------------------
__global__ void vq_prep_pack(const float* __restrict__ z,
                             const float* __restrict__ codebook,
                             float* __restrict__ zn, float* __restrict__ zz,
                             float* __restrict__ cc,
                             unsigned* __restrict__ chi, unsigned* __restrict__ clo,
                             unsigned* __restrict__ zhi, unsigned* __restrict__ zlo,
                             int* __restrict__ todo_cnt) {
    int gid = blockIdx.x * NTHREADS + threadIdx.x;
    if (gid == 0) *todo_cnt = 0;
    if (blockIdx.x < 64) {
        const float4* r4 = reinterpret_cast<const float4*>(codebook + (size_t)gid * D_DIM);
        float4 v[8];
#pragma unroll
        for (int h = 0; h < 8; ++h) v[h] = r4[h];
        float s = 0.f;
#pragma unroll
        for (int h = 0; h < 8; ++h) {   // d = 4h+0..3, sequential (exact order)
            s = fmaf(v[h].x, v[h].x, s);
            s = fmaf(v[h].y, v[h].y, s);
            s = fmaf(v[h].z, v[h].z, s);
            s = fmaf(v[h].w, v[h].w, s);
        }
        cc[gid] = s;
#pragma unroll
        for (int h = 0; h < 8; ++h) {
            unsigned hi0, lo0, hi1, lo1;
            pack_pair(v[h].x, v[h].y, hi0, lo0);
            pack_pair(v[h].z, v[h].w, hi1, lo1);
            chi[gid * 16 + 2 * h]     = hi0;  clo[gid * 16 + 2 * h]     = lo0;
            chi[gid * 16 + 2 * h + 1] = hi1;  clo[gid * 16 + 2 * h + 1] = lo1;
        }
    } else {
        int r = gid - N_CODES;                 // 0..8191
        const float4* r4 = reinterpret_cast<const float4*>(z + (size_t)r * D_DIM);
        float4 v[8];
#pragma unroll
        for (int h = 0; h < 8; ++h) v[h] = r4[h];
        float s = 0.f;
#pragma unroll
        for (int h = 0; h < 8; ++h) {
            s = fmaf(v[h].x, v[h].x, s);
            s = fmaf(v[h].y, v[h].y, s);
            s = fmaf(v[h].z, v[h].z, s);
            s = fmaf(v[h].w, v[h].w, s);
        }
        float norm = sqrtf(s);
        norm = fmaxf(norm, 1e-12f);
        float zs = 0.f;
        float4* zn4 = reinterpret_cast<float4*>(zn + (size_t)r * D_DIM);
#pragma unroll
        for (int h = 0; h < 8; ++h) {
            float4 w;
            w.x = v[h].x / norm;               // IEEE division, matches reference
            w.y = v[h].y / norm;
            w.z = v[h].z / norm;
            w.w = v[h].w / norm;
            zn4[h] = w;
            zs = fmaf(w.x, w.x, zs);
            zs = fmaf(w.y, w.y, zs);
            zs = fmaf(w.z, w.z, zs);
            zs = fmaf(w.w, w.w, zs);
            v[h] = w;                          // keep normalized for packing
        }
        zz[r] = zs;
#pragma unroll
        for (int h = 0; h < 8; ++h) {
            unsigned hi0, lo0, hi1, lo1;
            pack_pair(v[h].x, v[h].y, hi0, lo0);
            pack_pair(v[h].z, v[h].w, hi1, lo1);
            zhi[r * 16 + 2 * h]     = hi0;  zlo[r * 16 + 2 * h]     = lo0;
            zhi[r * 16 + 2 * h + 1] = hi1;  zlo[r * 16 + 2 * h + 1] = lo1;
        }
    }
}

// ---------------------------------------------------------------------------
// MFMA main (R10 structure + software pipeline, absmax-0 proven), templated
// on NSLICE. grid = 64 row-blocks x NSLICE. Block = 4 waves x 32 rows.
// VGPR_Count measured 36 at (256,4) -> 8 blocks/CU resident when grid allows.
// R9 lesson: never force launch_bounds above actual register comfort.
// ---------------------------------------------------------------------------
template <int NS>
__global__ __launch_bounds__(NTHREADS, 4)
void vq_mfma(const unsigned short* __restrict__ zhi,
             const unsigned short* __restrict__ zlo,
             const unsigned short* __restrict__ chi,
             const unsigned short* __restrict__ clo,
             const float* __restrict__ cc,
             float* __restrict__ pmin1, float* __restrict__ pmin2,
             int* __restrict__ pidx) {
    constexpr int SLICE_CODES = N_CODES / NS;
    constexpr int CT = SLICE_CODES / 16;

    const int tid  = threadIdx.x;
    const int wave = tid >> 6;
    const int lane = tid & 63;
    const int rb    = blockIdx.x & 63;
    const int slice = blockIdx.x >> 6;

    const int row_w = rb * 128 + wave * 32;    // wave's 32 rows (2 row-tiles)
    const int l15 = lane & 15;
    const int kg  = lane >> 4;                 // k-group 0..3
    const int kc  = kg * 8;

    const bf16x8 a_hi0 = *reinterpret_cast<const bf16x8*>(zhi + (size_t)(row_w + l15) * 32 + kc);
    const bf16x8 a_lo0 = *reinterpret_cast<const bf16x8*>(zlo + (size_t)(row_w + l15) * 32 + kc);
    const bf16x8 a_hi1 = *reinterpret_cast<const bf16x8*>(zhi + (size_t)(row_w + 16 + l15) * 32 + kc);
    const bf16x8 a_lo1 = *reinterpret_cast<const bf16x8*>(zlo + (size_t)(row_w + 16 + l15) * 32 + kc);

    float min1[8], min2[8];
    int   idx1[8];
#pragma unroll
    for (int q = 0; q < 8; ++q) { min1[q] = 3.4e38f; min2[q] = 3.4e38f; idx1[q] = 0x7FFFFFFF; }

    auto tile_update = [&](const bf16x8& bh, const bf16x8& bl, float ccv, int code) {
        f32x4 acc0 = {0.f, 0.f, 0.f, 0.f};
        f32x4 acc1 = {0.f, 0.f, 0.f, 0.f};
        acc0 = __builtin_amdgcn_mfma_f32_16x16x32_bf16(a_hi0, bh, acc0, 0, 0, 0);
        acc0 = __builtin_amdgcn_mfma_f32_16x16x32_bf16(a_hi0, bl, acc0, 0, 0, 0);
        acc0 = __builtin_amdgcn_mfma_f32_16x16x32_bf16(a_lo0, bh, acc0, 0, 0, 0);
        acc1 = __builtin_amdgcn_mfma_f32_16x16x32_bf16(a_hi1, bh, acc1, 0, 0, 0);
        acc1 = __builtin_amdgcn_mfma_f32_16x16x32_bf16(a_hi1, bl, acc1, 0, 0, 0);
        acc1 = __builtin_amdgcn_mfma_f32_16x16x32_bf16(a_lo1, bh, acc1, 0, 0, 0);
#pragma unroll
        for (int e = 0; e < 4; ++e) {
            float s0 = fmaf(-2.f, acc0[e], ccv);
            min2[e] = __builtin_amdgcn_fmed3f(s0, min1[e], min2[e]);
            bool lt0 = s0 < min1[e];
            min1[e] = lt0 ? s0 : min1[e];
            idx1[e] = lt0 ? code : idx1[e];

            float s1 = fmaf(-2.f, acc1[e], ccv);
            min2[4 + e] = __builtin_amdgcn_fmed3f(s1, min1[4 + e], min2[4 + e]);
            bool lt1 = s1 < min1[4 + e];
            min1[4 + e] = lt1 ? s1 : min1[4 + e];
            idx1[4 + e] = lt1 ? code : idx1[4 + e];
        }
    };

    // software-pipelined loop: prefetch ct+1 during ct (R10-proven)
    int code = slice * SLICE_CODES + l15;
    bf16x8 b_hi = *reinterpret_cast<const bf16x8*>(chi + (size_t)code * 32 + kc);
    bf16x8 b_lo = *reinterpret_cast<const bf16x8*>(clo + (size_t)code * 32 + kc);
    float  ccv  = cc[code];

    for (int ct = 0; ct < CT - 1; ++ct) {
        const int ncode = code + 16;
        const bf16x8 nb_hi = *reinterpret_cast<const bf16x8*>(chi + (size_t)ncode * 32 + kc);
        const bf16x8 nb_lo = *reinterpret_cast<const bf16x8*>(clo + (size_t)ncode * 32 + kc);
        const float  nccv  = cc[ncode];

        tile_update(b_hi, b_lo, ccv, code);

        b_hi = nb_hi; b_lo = nb_lo; ccv = nccv; code = ncode;
    }
    tile_update(b_hi, b_lo, ccv, code);   // peeled last tile

    // merge top-2 across the 16 column-lanes
#pragma unroll
    for (int q = 0; q < 8; ++q) {
        float m1 = min1[q], m2 = min2[q];
        int   i1 = idx1[q];
#pragma unroll
        for (int off = 1; off < 16; off <<= 1) {
            float o1 = __shfl_xor(m1, off);
            float o2 = __shfl_xor(m2, off);
            int   oi = __shfl_xor(i1, off);
            float nm2 = fminf(fmaxf(m1, o1), fminf(m2, o2));
            if (o1 < m1 || (o1 == m1 && oi < i1)) { m1 = o1; i1 = oi; }
            m2 = nm2;
        }
        min1[q] = m1; min2[q] = m2; idx1[q] = i1;
    }
    if (l15 == 0) {
#pragma unroll
        for (int q = 0; q < 8; ++q) {
            const int rt = q >> 2, e = q & 3;
            const int row = row_w + rt * 16 + kg * 4 + e;
            pmin1[slice * M_ROWS + row] = min1[q];
            pmin2[slice * M_ROWS + row] = min2[q];
            pidx [slice * M_ROWS + row] = idx1[q];
        }
    }
}

// ---------------------------------------------------------------------------
// Merge slices (templated on NSLICE); certified rows finalize; rest -> todo.
// ---------------------------------------------------------------------------
template <int NS>
__global__ void vq_merge(const float* __restrict__ codebook,
                         const float* __restrict__ pmin1,
                         const float* __restrict__ pmin2,
                         const int* __restrict__ pidx,
                         float* __restrict__ zq, float* __restrict__ idx_out,
                         int* __restrict__ todo_cnt, int* __restrict__ todo) {
    const int row = blockIdx.x * NTHREADS + threadIdx.x;
    float m1 = pmin1[row], m2 = pmin2[row];
    int   i1 = pidx[row];
#pragma unroll
    for (int s = 1; s < NS; ++s) {
        float o1 = pmin1[s * M_ROWS + row];
        float o2 = pmin2[s * M_ROWS + row];
        int   oi = pidx [s * M_ROWS + row];
        float nm2 = fminf(fmaxf(m1, o1), fminf(m2, o2));
        if (o1 < m1) { m1 = o1; i1 = oi; }   // slices ascend in code index
        m2 = nm2;
    }
    if (m2 - m1 > DELTA_MARGIN) {
        idx_out[row] = (float)i1;
        const float4* src = reinterpret_cast<const float4*>(codebook + (size_t)i1 * D_DIM);
        float4* dst = reinterpret_cast<float4*>(zq + (size_t)row * D_DIM);
#pragma unroll
        for (int k = 0; k < 8; ++k) dst[k] = src[k];
    } else {
        int p = atomicAdd(todo_cnt, 1);
        todo[p] = row;
    }
}

// ---------------------------------------------------------------------------
// Cleanup SCAN (R8-validated): work item = (todo-slot, chunk).
// ---------------------------------------------------------------------------
__global__ __launch_bounds__(NTHREADS)
void vq_cleanup_scan(const float* __restrict__ zn, const float* __restrict__ zz,
                     const float* __restrict__ codebook, const float* __restrict__ cc,
                     const int* __restrict__ todo_cnt, const int* __restrict__ todo,
                     float* __restrict__ cpmin, int* __restrict__ cpidx) {
    const int n = *todo_cnt;
    const int chunk = blockIdx.x & (NCHUNK - 1);
    const int slot  = blockIdx.x >> 4;            // 0..SCAN_SLOTS-1
    const int tid   = threadIdx.x;
    const int cbase = chunk * CHUNK_CODES;

    __shared__ float sv[4];
    __shared__ int   si[4];

    for (int i = slot; i < n; i += SCAN_SLOTS) {
        const int row = todo[i];

        float zr[D_DIM];
#pragma unroll
        for (int d = 0; d < D_DIM; ++d) zr[d] = zn[(size_t)row * D_DIM + d];
        const float zzv = zz[row];

        float bm = 3.4e38f;
        int   bi = 0x7FFFFFFF;
#pragma unroll
        for (int k = 0; k < CHUNK_CODES / NTHREADS; ++k) {   // 4 iters
            const int c = cbase + tid + (k << 8);            // ascending per thread
            const float4* cb = reinterpret_cast<const float4*>(codebook + (size_t)c * D_DIM);
            float dot = 0.f;
#pragma unroll
            for (int h = 0; h < 8; ++h) {
                float4 v = cb[h];
                dot = fmaf(zr[4 * h + 0], v.x, dot);
                dot = fmaf(zr[4 * h + 1], v.y, dot);
                dot = fmaf(zr[4 * h + 2], v.z, dot);
                dot = fmaf(zr[4 * h + 3], v.w, dot);
            }
            float t = zzv + cc[c];
            float dist = fmaf(-2.f, dot, t);
            if (dist < bm || (dist == bm && c < bi)) { bm = dist; bi = c; }
        }

#pragma unroll
        for (int off = 32; off >= 1; off >>= 1) {
            float ov = __shfl_xor(bm, off);
            int   oi = __shfl_xor(bi, off);
            if (ov < bm || (ov == bm && oi < bi)) { bm = ov; bi = oi; }
        }
        if ((tid & 63) == 0) { sv[tid >> 6] = bm; si[tid >> 6] = bi; }
        __syncthreads();
        if (tid == 0) {
            float v = sv[0]; int idx = si[0];
#pragma unroll
            for (int w = 1; w < 4; ++w) {
                if (sv[w] < v || (sv[w] == v && si[w] < idx)) { v = sv[w]; idx = si[w]; }
            }
            cpmin[chunk * M_ROWS + row] = v;
            cpidx[chunk * M_ROWS + row] = idx;
        }
        __syncthreads();
    }
}

// ---------------------------------------------------------------------------
// Cleanup FINAL (R8-validated): one thread per todo row.
// ---------------------------------------------------------------------------
__global__ __launch_bounds__(NTHREADS)
void vq_cleanup_final(const float* __restrict__ codebook,
                      const int* __restrict__ todo_cnt, const int* __restrict__ todo,
                      const float* __restrict__ cpmin, const int* __restrict__ cpidx,
                      float* __restrict__ zq, float* __restrict__ idx_out) {
    const int n = *todo_cnt;
    for (int i = blockIdx.x * NTHREADS + threadIdx.x; i < n; i += gridDim.x * NTHREADS) {
        const int row = todo[i];
        float bv = cpmin[row];
        int   bi = cpidx[row];
#pragma unroll
        for (int c = 1; c < NCHUNK; ++c) {
            float v = cpmin[c * M_ROWS + row];
            int   j = cpidx[c * M_ROWS + row];
            if (v < bv || (v == bv && j < bi)) { bv = v; bi = j; }
        }
        idx_out[row] = (float)bi;
        const float4* src = reinterpret_cast<const float4*>(codebook + (size_t)bi * D_DIM);
        float4* dst = reinterpret_cast<float4*>(zq + (size_t)row * D_DIM);
#pragma unroll
        for (int k = 0; k < 8; ++k) dst[k] = src[k];
    }
}

// ===========================================================================
// ===== Fallback path (verbatim R3, proven 175 us / absmax 0) ==============
// ===========================================================================
#define R_TILE   32
#define NSLICE_F 4
#define SLICE_CODES_F (N_CODES / NSLICE_F)
#define C_TILE   256
#define N_TILES_F (SLICE_CODES_F / C_TILE)
#define CB_PAD   36

__global__ void vq_prep_basic(const float* __restrict__ z,
                              const float* __restrict__ codebook,
                              float* __restrict__ zn,
                              float* __restrict__ zz,
                              float* __restrict__ cc) {
    int gid = blockIdx.x * NTHREADS + threadIdx.x;
    if (blockIdx.x < 64) {
        const float* row = codebook + (size_t)gid * D_DIM;
        float s = 0.f;
#pragma unroll
        for (int d = 0; d < D_DIM; ++d) s = fmaf(row[d], row[d], s);
        cc[gid] = s;
    } else {
        int r = gid - N_CODES;
        const float* row = z + (size_t)r * D_DIM;
        float s = 0.f;
#pragma unroll
        for (int d = 0; d < D_DIM; ++d) { float v = row[d]; s = fmaf(v, v, s); }
        float norm = sqrtf(s);
        norm = fmaxf(norm, 1e-12f);
        float zs = 0.f;
#pragma unroll
        for (int d = 0; d < D_DIM; ++d) {
            float v = row[d] / norm;
            zn[(size_t)r * D_DIM + d] = v;
            zs = fmaf(v, v, zs);
        }
        zz[r] = zs;
    }
}

__global__ __launch_bounds__(NTHREADS, 4)
void vq_main_basic(const float* __restrict__ zn, const float* __restrict__ zz,
                   const float* __restrict__ codebook, const float* __restrict__ cc,
                   float* __restrict__ pminv, int* __restrict__ pmini) {
    __shared__ float cb_lds[C_TILE * CB_PAD];
    __shared__ float zt[R_TILE * D_DIM];
    const int tid = threadIdx.x;
    const int rb = blockIdx.x & 255;
    const int slice = blockIdx.x >> 8;
    const int rg = tid >> 6;
    const int cg = tid & 63;
    const int row_base = rb * R_TILE;
    const int code_base = slice * SLICE_CODES_F;
    const int wrow = row_base + rg * 8;
    {
        float4 v = *reinterpret_cast<const float4*>(zn + (size_t)row_base * D_DIM + tid * 4);
        *reinterpret_cast<float4*>(&zt[tid * 4]) = v;
    }
    float zzr[8];
#pragma unroll
    for (int r = 0; r < 8; ++r) zzr[r] = zz[wrow + r];
    float minv[8]; int mini[8];
#pragma unroll
    for (int r = 0; r < 8; ++r) { minv[r] = 3.4e38f; mini[r] = 0; }
    for (int t = 0; t < N_TILES_F; ++t) {
        const int base = code_base + t * C_TILE;
        __syncthreads();
        {
            const float4* src = reinterpret_cast<const float4*>(codebook + (size_t)(base + tid) * D_DIM);
            float* dstf = &cb_lds[tid * CB_PAD];
#pragma unroll
            for (int k = 0; k < 8; ++k) *reinterpret_cast<float4*>(dstf + k * 4) = src[k];
        }
        __syncthreads();
        float acc[8][4];
#pragma unroll
        for (int r = 0; r < 8; ++r)
#pragma unroll
            for (int j = 0; j < 4; ++j) acc[r][j] = 0.f;
#pragma unroll
        for (int dc = 0; dc < 8; ++dc) {
            float4 cb4[4];
#pragma unroll
            for (int j = 0; j < 4; ++j)
                cb4[j] = *reinterpret_cast<const float4*>(&cb_lds[(cg + 64 * j) * CB_PAD + dc * 4]);
#pragma unroll
            for (int r = 0; r < 8; ++r) {
                const float4 zv = *reinterpret_cast<const float4*>(&zt[(rg * 8 + r) * D_DIM + dc * 4]);
#pragma unroll
                for (int j = 0; j < 4; ++j) {
                    float a = acc[r][j];
                    a = fmaf(zv.x, cb4[j].x, a);
                    a = fmaf(zv.y, cb4[j].y, a);
                    a = fmaf(zv.z, cb4[j].z, a);
                    a = fmaf(zv.w, cb4[j].w, a);
                    acc[r][j] = a;
                }
            }
        }
#pragma unroll
        for (int j = 0; j < 4; ++j) {
            const int code = base + cg + 64 * j;
            const float ccj = cc[code];
#pragma unroll
            for (int r = 0; r < 8; ++r) {
                float tsum = zzr[r] + ccj;
                float dist = fmaf(-2.f, acc[r][j], tsum);
                if (dist < minv[r]) { minv[r] = dist; mini[r] = code; }
            }
        }
    }
#pragma unroll
    for (int r = 0; r < 8; ++r) {
        float v = minv[r]; int i = mini[r];
#pragma unroll
        for (int off = 32; off >= 1; off >>= 1) {
            float ov = __shfl_xor(v, off);
            int   oi = __shfl_xor(i, off);
            if (ov < v || (ov == v && oi < i)) { v = ov; i = oi; }
        }
        minv[r] = v; mini[r] = i;
    }
    if (cg == 0) {
#pragma unroll
        for (int r = 0; r < 8; ++r) {
            pminv[slice * M_ROWS + wrow + r] = minv[r];
            pmini[slice * M_ROWS + wrow + r] = mini[r];
        }
    }
}

__global__ void vq_final_basic(const float* __restrict__ codebook,
                               const float* __restrict__ pminv,
                               const int* __restrict__ pmini,
                               float* __restrict__ zq, float* __restrict__ idx_out) {
    int row = blockIdx.x * NTHREADS + threadIdx.x;
    float bv = pminv[row];
    int   bi = pmini[row];
#pragma unroll
    for (int s = 1; s < NSLICE_F; ++s) {
        float v = pminv[s * M_ROWS + row];
        int   i = pmini[s * M_ROWS + row];
        if (v < bv || (v == bv && i < bi)) { bv = v; bi = i; }
    }
    idx_out[row] = (float)bi;
    const float4* src = reinterpret_cast<const float4*>(codebook + (size_t)bi * D_DIM);
    float4* dst = reinterpret_cast<float4*>(zq + (size_t)row * D_DIM);
#pragma unroll
    for (int k = 0; k < 8; ++k) dst[k] = src[k];
}

// ===========================================================================
static size_t ws_needed(int nslice) {
    return 4ull * (N_CODES + M_ROWS + 3ull * (size_t)nslice * M_ROWS) +
           4ull * (4 + M_ROWS) +
           2ull * (2ull * N_CODES * D_DIM + 2ull * M_ROWS * D_DIM);
}

template <int NS>
static void launch_mfma_path(const float* z, const float* codebook,
                             float* zn, float* zq_out, float* idx_out,
                             void* d_ws, hipStream_t stream) {
    float* cc    = (float*)d_ws;
    float* zz    = cc + N_CODES;
    float* pmin1 = zz + M_ROWS;
    float* pmin2 = pmin1 + (size_t)NS * M_ROWS;
    int*   pidx  = (int*)(pmin2 + (size_t)NS * M_ROWS);
    int*   todo_cnt = pidx + (size_t)NS * M_ROWS;
    int*   todo  = todo_cnt + 4;
    unsigned* chi = (unsigned*)(todo + M_ROWS);
    unsigned* clo = chi + (size_t)N_CODES * D_DIM / 2;
    unsigned* zhi = clo + (size_t)N_CODES * D_DIM / 2;
    unsigned* zlo = zhi + (size_t)M_ROWS * D_DIM / 2;

    // cleanup partials reuse pmin1/pidx (consumed by vq_merge before scan)
    float* cpmin = pmin1;
    int*   cpidx = pidx;

    vq_prep_pack<<<96, NTHREADS, 0, stream>>>(z, codebook, zn, zz, cc,
                                              chi, clo, zhi, zlo, todo_cnt);
    vq_mfma<NS><<<64 * NS, NTHREADS, 0, stream>>>(
        (const unsigned short*)zhi, (const unsigned short*)zlo,
        (const unsigned short*)chi, (const unsigned short*)clo,
        cc, pmin1, pmin2, pidx);
    vq_merge<NS><<<M_ROWS / NTHREADS, NTHREADS, 0, stream>>>(
        codebook, pmin1, pmin2, pidx, zq_out, idx_out, todo_cnt, todo);
    vq_cleanup_scan<<<SCAN_SLOTS * NCHUNK, NTHREADS, 0, stream>>>(
        zn, zz, codebook, cc, todo_cnt, todo, cpmin, cpidx);
    vq_cleanup_final<<<32, NTHREADS, 0, stream>>>(
        codebook, todo_cnt, todo, cpmin, cpidx, zq_out, idx_out);
}

extern "C" void kernel_launch(void* const* d_in, const int* in_sizes, int n_in,
                              void* d_out, int out_size, void* d_ws, size_t ws_size,
                              hipStream_t stream) {
    const float* z        = (const float*)d_in[0];   // [8,1024,32]
    const float* codebook = (const float*)d_in[1];   // [16384,32]

    float* out     = (float*)d_out;
    float* zq_out  = out;                            // 262144 floats
    float* idx_out = out + (size_t)M_ROWS * D_DIM;   // 8192 floats
    float* zn      = zq_out;                         // zn lives in zq region

    if (ws_size >= ws_needed(32)) {
        launch_mfma_path<32>(z, codebook, zn, zq_out, idx_out, d_ws, stream);
    } else if (ws_size >= ws_needed(16)) {
        launch_mfma_path<16>(z, codebook, zn, zq_out, idx_out, d_ws, stream);
    } else {
        // Fallback: proven R3 path (~350 KB ws)
        float* cc    = (float*)d_ws;
        float* zz    = cc + N_CODES;
        float* pminv = zz + M_ROWS;
        int*   pmini = (int*)(pminv + (size_t)NSLICE_F * M_ROWS);

        vq_prep_basic<<<96, NTHREADS, 0, stream>>>(z, codebook, zn, zz, cc);
        vq_main_basic<<<256 * NSLICE_F, NTHREADS, 0, stream>>>(zn, zz, codebook, cc,
                                                               pminv, pmini);
        vq_final_basic<<<M_ROWS / NTHREADS, NTHREADS, 0, stream>>>(codebook, pminv,
                                                                   pmini, zq_out, idx_out);
    }
}

// Round 12
// 76.098 us; speedup vs baseline: 1.1310x; 1.1310x over previous
//
#include <hip/hip_runtime.h>
#include <math.h>

// Problem constants
#define M_ROWS   8192     // B*S
#define N_CODES  16384
#define D_DIM    32
#define NTHREADS 256

// Certification margin (R7/R8/R9/R10: absmax 0 at this margin).
// Error budget: ours |dist err| <= 3.4e-5, ref ~5e-6; certify iff gap > 8.2e-5;
// 2e-4 = 2.4x cushion.
#define DELTA_MARGIN  2e-4f

// ===== cleanup parameters =====
#define NCHUNK       16
#define CHUNK_CODES  (N_CODES / NCHUNK)       // 1024
#define SCAN_SLOTS   256                       // row-slot stride in scan grid

typedef short bf16x8 __attribute__((ext_vector_type(8)));  // 8 bf16
typedef float f32x4  __attribute__((ext_vector_type(4)));

// round-to-nearest-even fp32 -> bf16 bits
__device__ inline unsigned short bf16_rne(float f) {
    unsigned u = __float_as_uint(f);
    unsigned r = u + 0x7FFFu + ((u >> 16) & 1u);
    return (unsigned short)(r >> 16);
}

__device__ inline void pack_pair(float f0, float f1, unsigned& hi, unsigned& lo) {
    unsigned short h0 = bf16_rne(f0), h1 = bf16_rne(f1);
    float r0 = f0 - __uint_as_float((unsigned)h0 << 16);
    float r1 = f1 - __uint_as_float((unsigned)h1 << 16);
    unsigned short l0 = bf16_rne(r0), l1 = bf16_rne(r1);
    hi = (unsigned)h0 | ((unsigned)h1 << 16);
    lo = (unsigned)l0 | ((unsigned)l1 << 16);
}

// ---------------------------------------------------------------------------
// Prep+pack (R11 vectorized version, absmax-0): adds cch = -0.5*cc output.
//   blocks 0..63: cc/cch + codebook hi/lo bf16 pack
//   blocks 64..95: normalize z -> zn (d_out), zz, z hi/lo bf16 pack
// ---------------------------------------------------------------------------
__global__ void vq_prep_pack(const float* __restrict__ z,
                             const float* __restrict__ codebook,
                             float* __restrict__ zn, float* __restrict__ zz,
                             float* __restrict__ cc, float* __restrict__ cch,
                             unsigned* __restrict__ chi, unsigned* __restrict__ clo,
                             unsigned* __restrict__ zhi, unsigned* __restrict__ zlo,
                             int* __restrict__ todo_cnt) {
    int gid = blockIdx.x * NTHREADS + threadIdx.x;
    if (gid == 0) *todo_cnt = 0;
    if (blockIdx.x < 64) {
        const float4* r4 = reinterpret_cast<const float4*>(codebook + (size_t)gid * D_DIM);
        float4 v[8];
#pragma unroll
        for (int h = 0; h < 8; ++h) v[h] = r4[h];
        float s = 0.f;
#pragma unroll
        for (int h = 0; h < 8; ++h) {   // d = 4h+0..3, sequential (exact order)
            s = fmaf(v[h].x, v[h].x, s);
            s = fmaf(v[h].y, v[h].y, s);
            s = fmaf(v[h].z, v[h].z, s);
            s = fmaf(v[h].w, v[h].w, s);
        }
        cc[gid]  = s;
        cch[gid] = -0.5f * s;   // exact scaling
#pragma unroll
        for (int h = 0; h < 8; ++h) {
            unsigned hi0, lo0, hi1, lo1;
            pack_pair(v[h].x, v[h].y, hi0, lo0);
            pack_pair(v[h].z, v[h].w, hi1, lo1);
            chi[gid * 16 + 2 * h]     = hi0;  clo[gid * 16 + 2 * h]     = lo0;
            chi[gid * 16 + 2 * h + 1] = hi1;  clo[gid * 16 + 2 * h + 1] = lo1;
        }
    } else {
        int r = gid - N_CODES;                 // 0..8191
        const float4* r4 = reinterpret_cast<const float4*>(z + (size_t)r * D_DIM);
        float4 v[8];
#pragma unroll
        for (int h = 0; h < 8; ++h) v[h] = r4[h];
        float s = 0.f;
#pragma unroll
        for (int h = 0; h < 8; ++h) {
            s = fmaf(v[h].x, v[h].x, s);
            s = fmaf(v[h].y, v[h].y, s);
            s = fmaf(v[h].z, v[h].z, s);
            s = fmaf(v[h].w, v[h].w, s);
        }
        float norm = sqrtf(s);
        norm = fmaxf(norm, 1e-12f);
        float zs = 0.f;
        float4* zn4 = reinterpret_cast<float4*>(zn + (size_t)r * D_DIM);
#pragma unroll
        for (int h = 0; h < 8; ++h) {
            float4 w;
            w.x = v[h].x / norm;               // IEEE division, matches reference
            w.y = v[h].y / norm;
            w.z = v[h].z / norm;
            w.w = v[h].w / norm;
            zn4[h] = w;
            zs = fmaf(w.x, w.x, zs);
            zs = fmaf(w.y, w.y, zs);
            zs = fmaf(w.z, w.z, zs);
            zs = fmaf(w.w, w.w, zs);
            v[h] = w;                          // keep normalized for packing
        }
        zz[r] = zs;
#pragma unroll
        for (int h = 0; h < 8; ++h) {
            unsigned hi0, lo0, hi1, lo1;
            pack_pair(v[h].x, v[h].y, hi0, lo0);
            pack_pair(v[h].z, v[h].w, hi1, lo1);
            zhi[r * 16 + 2 * h]     = hi0;  zlo[r * 16 + 2 * h]     = lo0;
            zhi[r * 16 + 2 * h + 1] = hi1;  zlo[r * 16 + 2 * h + 1] = lo1;
        }
    }
}

// ---------------------------------------------------------------------------
// MFMA main v4: R10 structure (NSLICE 16, launch_bounds(256,4)) with
//  (a) -0.5*cc folded into acc init -> key = dot - 0.5*cc, argMAX tracking
//      (R9-validated semantics; saves the per-element fmaf: 4 VALU/elem)
//  (b) tile loop unrolled x2: two independent 16-code tiles per iteration ->
//      two independent 6-MFMA chains overlap in the matrix pipe; argmin of
//      pair A overlaps MFMA of pair B. Prefetch next pair (32 codes ahead).
// R9 lesson kept: launch_bounds stays (256,4); grid-limited 4 blocks/CU, so
// VGPR up to 128 is free. Watch WRITE_SIZE for spill (falsifier).
// ---------------------------------------------------------------------------
template <int NS>
__global__ __launch_bounds__(NTHREADS, 4)
void vq_mfma(const unsigned short* __restrict__ zhi,
             const unsigned short* __restrict__ zlo,
             const unsigned short* __restrict__ chi,
             const unsigned short* __restrict__ clo,
             const float* __restrict__ cch,
             float* __restrict__ pmax1, float* __restrict__ pmax2,
             int* __restrict__ pidx) {
    constexpr int SLICE_CODES = N_CODES / NS;   // 1024 at NS=16
    constexpr int NPAIR = SLICE_CODES / 32;     // 32 double-tiles

    const int tid  = threadIdx.x;
    const int wave = tid >> 6;
    const int lane = tid & 63;
    const int rb    = blockIdx.x & 63;
    const int slice = blockIdx.x >> 6;

    const int row_w = rb * 128 + wave * 32;    // wave's 32 rows (2 row-tiles)
    const int l15 = lane & 15;
    const int kg  = lane >> 4;                 // k-group 0..3
    const int kc  = kg * 8;

    const bf16x8 a_hi0 = *reinterpret_cast<const bf16x8*>(zhi + (size_t)(row_w + l15) * 32 + kc);
    const bf16x8 a_lo0 = *reinterpret_cast<const bf16x8*>(zlo + (size_t)(row_w + l15) * 32 + kc);
    const bf16x8 a_hi1 = *reinterpret_cast<const bf16x8*>(zhi + (size_t)(row_w + 16 + l15) * 32 + kc);
    const bf16x8 a_lo1 = *reinterpret_cast<const bf16x8*>(zlo + (size_t)(row_w + 16 + l15) * 32 + kc);

    float max1[8], max2[8];
    int   idx1[8];
#pragma unroll
    for (int q = 0; q < 8; ++q) { max1[q] = -3.4e38f; max2[q] = -3.4e38f; idx1[q] = 0x7FFFFFFF; }

    // 6 MFMAs for one 16-code tile (both row-tiles), acc pre-loaded with -cc/2
    auto mfma6 = [&](const bf16x8& bh, const bf16x8& bl, float cchv,
                     f32x4& acc0, f32x4& acc1) {
        acc0 = {cchv, cchv, cchv, cchv};
        acc1 = {cchv, cchv, cchv, cchv};
        acc0 = __builtin_amdgcn_mfma_f32_16x16x32_bf16(a_hi0, bh, acc0, 0, 0, 0);
        acc0 = __builtin_amdgcn_mfma_f32_16x16x32_bf16(a_hi0, bl, acc0, 0, 0, 0);
        acc0 = __builtin_amdgcn_mfma_f32_16x16x32_bf16(a_lo0, bh, acc0, 0, 0, 0);
        acc1 = __builtin_amdgcn_mfma_f32_16x16x32_bf16(a_hi1, bh, acc1, 0, 0, 0);
        acc1 = __builtin_amdgcn_mfma_f32_16x16x32_bf16(a_hi1, bl, acc1, 0, 0, 0);
        acc1 = __builtin_amdgcn_mfma_f32_16x16x32_bf16(a_lo1, bh, acc1, 0, 0, 0);
    };
    // argmax(top-2) update: 4 VALU per element (med3 + cmp + 2 cndmask)
    auto argup = [&](const f32x4& acc0, const f32x4& acc1, int code) {
#pragma unroll
        for (int e = 0; e < 4; ++e) {
            float s0 = acc0[e];
            max2[e] = __builtin_amdgcn_fmed3f(s0, max1[e], max2[e]);
            bool gt0 = s0 > max1[e];
            max1[e] = gt0 ? s0 : max1[e];
            idx1[e] = gt0 ? code : idx1[e];

            float s1 = acc1[e];
            max2[4 + e] = __builtin_amdgcn_fmed3f(s1, max1[4 + e], max2[4 + e]);
            bool gt1 = s1 > max1[4 + e];
            max1[4 + e] = gt1 ? s1 : max1[4 + e];
            idx1[4 + e] = gt1 ? code : idx1[4 + e];
        }
    };

    // software-pipelined loop over 32 tile-pairs: prefetch pair p+1 during p
    int code = slice * SLICE_CODES + l15;
    bf16x8 b0h = *reinterpret_cast<const bf16x8*>(chi + (size_t)code * 32 + kc);
    bf16x8 b0l = *reinterpret_cast<const bf16x8*>(clo + (size_t)code * 32 + kc);
    bf16x8 b1h = *reinterpret_cast<const bf16x8*>(chi + (size_t)(code + 16) * 32 + kc);
    bf16x8 b1l = *reinterpret_cast<const bf16x8*>(clo + (size_t)(code + 16) * 32 + kc);
    float  c0  = cch[code];
    float  c1  = cch[code + 16];

    for (int p = 0; p < NPAIR - 1; ++p) {
        const int ncode = code + 32;
        const bf16x8 nb0h = *reinterpret_cast<const bf16x8*>(chi + (size_t)ncode * 32 + kc);
        const bf16x8 nb0l = *reinterpret_cast<const bf16x8*>(clo + (size_t)ncode * 32 + kc);
        const bf16x8 nb1h = *reinterpret_cast<const bf16x8*>(chi + (size_t)(ncode + 16) * 32 + kc);
        const bf16x8 nb1l = *reinterpret_cast<const bf16x8*>(clo + (size_t)(ncode + 16) * 32 + kc);
        const float  nc0  = cch[ncode];
        const float  nc1  = cch[ncode + 16];

        f32x4 a00, a01, a10, a11;
        mfma6(b0h, b0l, c0, a00, a01);     // chain A
        mfma6(b1h, b1l, c1, a10, a11);     // chain B (independent)
        argup(a00, a01, code);
        argup(a10, a11, code + 16);

        b0h = nb0h; b0l = nb0l; b1h = nb1h; b1l = nb1l;
        c0 = nc0; c1 = nc1; code = ncode;
    }
    {   // peeled last pair
        f32x4 a00, a01, a10, a11;
        mfma6(b0h, b0l, c0, a00, a01);
        mfma6(b1h, b1l, c1, a10, a11);
        argup(a00, a01, code);
        argup(a10, a11, code + 16);
    }

    // merge top-2 (max) across the 16 column-lanes (R9-validated)
#pragma unroll
    for (int q = 0; q < 8; ++q) {
        float m1 = max1[q], m2 = max2[q];
        int   i1 = idx1[q];
#pragma unroll
        for (int off = 1; off < 16; off <<= 1) {
            float o1 = __shfl_xor(m1, off);
            float o2 = __shfl_xor(m2, off);
            int   oi = __shfl_xor(i1, off);
            float nm2 = fmaxf(fminf(m1, o1), fmaxf(m2, o2));
            if (o1 > m1 || (o1 == m1 && oi < i1)) { m1 = o1; i1 = oi; }
            m2 = nm2;
        }
        max1[q] = m1; max2[q] = m2; idx1[q] = i1;
    }
    if (l15 == 0) {
#pragma unroll
        for (int q = 0; q < 8; ++q) {
            const int rt = q >> 2, e = q & 3;
            const int row = row_w + rt * 16 + kg * 4 + e;
            pmax1[slice * M_ROWS + row] = max1[q];
            pmax2[slice * M_ROWS + row] = max2[q];
            pidx [slice * M_ROWS + row] = idx1[q];
        }
    }
}

// ---------------------------------------------------------------------------
// Merge slices (max-key, R9-validated); certified rows finalize; rest -> todo.
// ---------------------------------------------------------------------------
template <int NS>
__global__ void vq_merge(const float* __restrict__ codebook,
                         const float* __restrict__ pmax1,
                         const float* __restrict__ pmax2,
                         const int* __restrict__ pidx,
                         float* __restrict__ zq, float* __restrict__ idx_out,
                         int* __restrict__ todo_cnt, int* __restrict__ todo) {
    const int row = blockIdx.x * NTHREADS + threadIdx.x;
    float m1 = pmax1[row], m2 = pmax2[row];
    int   i1 = pidx[row];
#pragma unroll
    for (int s = 1; s < NS; ++s) {
        float o1 = pmax1[s * M_ROWS + row];
        float o2 = pmax2[s * M_ROWS + row];
        int   oi = pidx [s * M_ROWS + row];
        float nm2 = fmaxf(fminf(m1, o1), fmaxf(m2, o2));
        if (o1 > m1) { m1 = o1; i1 = oi; }   // slices ascend in code index
        m2 = nm2;
    }
    if (2.0f * (m1 - m2) > DELTA_MARGIN) {
        idx_out[row] = (float)i1;
        const float4* src = reinterpret_cast<const float4*>(codebook + (size_t)i1 * D_DIM);
        float4* dst = reinterpret_cast<float4*>(zq + (size_t)row * D_DIM);
#pragma unroll
        for (int k = 0; k < 8; ++k) dst[k] = src[k];
    } else {
        int p = atomicAdd(todo_cnt, 1);
        todo[p] = row;
    }
}

// ---------------------------------------------------------------------------
// Cleanup SCAN (R8-validated): work item = (todo-slot, chunk). Exact fp32.
// ---------------------------------------------------------------------------
__global__ __launch_bounds__(NTHREADS)
void vq_cleanup_scan(const float* __restrict__ zn, const float* __restrict__ zz,
                     const float* __restrict__ codebook, const float* __restrict__ cc,
                     const int* __restrict__ todo_cnt, const int* __restrict__ todo,
                     float* __restrict__ cpmin, int* __restrict__ cpidx) {
    const int n = *todo_cnt;
    const int chunk = blockIdx.x & (NCHUNK - 1);
    const int slot  = blockIdx.x >> 4;            // 0..SCAN_SLOTS-1
    const int tid   = threadIdx.x;
    const int cbase = chunk * CHUNK_CODES;

    __shared__ float sv[4];
    __shared__ int   si[4];

    for (int i = slot; i < n; i += SCAN_SLOTS) {
        const int row = todo[i];

        float zr[D_DIM];
#pragma unroll
        for (int d = 0; d < D_DIM; ++d) zr[d] = zn[(size_t)row * D_DIM + d];
        const float zzv = zz[row];

        float bm = 3.4e38f;
        int   bi = 0x7FFFFFFF;
#pragma unroll
        for (int k = 0; k < CHUNK_CODES / NTHREADS; ++k) {   // 4 iters
            const int c = cbase + tid + (k << 8);            // ascending per thread
            const float4* cb = reinterpret_cast<const float4*>(codebook + (size_t)c * D_DIM);
            float dot = 0.f;
#pragma unroll
            for (int h = 0; h < 8; ++h) {
                float4 v = cb[h];
                dot = fmaf(zr[4 * h + 0], v.x, dot);
                dot = fmaf(zr[4 * h + 1], v.y, dot);
                dot = fmaf(zr[4 * h + 2], v.z, dot);
                dot = fmaf(zr[4 * h + 3], v.w, dot);
            }
            float t = zzv + cc[c];
            float dist = fmaf(-2.f, dot, t);
            if (dist < bm || (dist == bm && c < bi)) { bm = dist; bi = c; }
        }

#pragma unroll
        for (int off = 32; off >= 1; off >>= 1) {
            float ov = __shfl_xor(bm, off);
            int   oi = __shfl_xor(bi, off);
            if (ov < bm || (ov == bm && oi < bi)) { bm = ov; bi = oi; }
        }
        if ((tid & 63) == 0) { sv[tid >> 6] = bm; si[tid >> 6] = bi; }
        __syncthreads();
        if (tid == 0) {
            float v = sv[0]; int idx = si[0];
#pragma unroll
            for (int w = 1; w < 4; ++w) {
                if (sv[w] < v || (sv[w] == v && si[w] < idx)) { v = sv[w]; idx = si[w]; }
            }
            cpmin[chunk * M_ROWS + row] = v;
            cpidx[chunk * M_ROWS + row] = idx;
        }
        __syncthreads();
    }
}

// ---------------------------------------------------------------------------
// Cleanup FINAL (R8-validated): one thread per todo row.
// ---------------------------------------------------------------------------
__global__ __launch_bounds__(NTHREADS)
void vq_cleanup_final(const float* __restrict__ codebook,
                      const int* __restrict__ todo_cnt, const int* __restrict__ todo,
                      const float* __restrict__ cpmin, const int* __restrict__ cpidx,
                      float* __restrict__ zq, float* __restrict__ idx_out) {
    const int n = *todo_cnt;
    for (int i = blockIdx.x * NTHREADS + threadIdx.x; i < n; i += gridDim.x * NTHREADS) {
        const int row = todo[i];
        float bv = cpmin[row];
        int   bi = cpidx[row];
#pragma unroll
        for (int c = 1; c < NCHUNK; ++c) {
            float v = cpmin[c * M_ROWS + row];
            int   j = cpidx[c * M_ROWS + row];
            if (v < bv || (v == bv && j < bi)) { bv = v; bi = j; }
        }
        idx_out[row] = (float)bi;
        const float4* src = reinterpret_cast<const float4*>(codebook + (size_t)bi * D_DIM);
        float4* dst = reinterpret_cast<float4*>(zq + (size_t)row * D_DIM);
#pragma unroll
        for (int k = 0; k < 8; ++k) dst[k] = src[k];
    }
}

// ===========================================================================
// ===== Fallback path (verbatim R3, proven 175 us / absmax 0) ==============
// ===========================================================================
#define R_TILE   32
#define NSLICE_F 4
#define SLICE_CODES_F (N_CODES / NSLICE_F)
#define C_TILE   256
#define N_TILES_F (SLICE_CODES_F / C_TILE)
#define CB_PAD   36

__global__ void vq_prep_basic(const float* __restrict__ z,
                              const float* __restrict__ codebook,
                              float* __restrict__ zn,
                              float* __restrict__ zz,
                              float* __restrict__ cc) {
    int gid = blockIdx.x * NTHREADS + threadIdx.x;
    if (blockIdx.x < 64) {
        const float* row = codebook + (size_t)gid * D_DIM;
        float s = 0.f;
#pragma unroll
        for (int d = 0; d < D_DIM; ++d) s = fmaf(row[d], row[d], s);
        cc[gid] = s;
    } else {
        int r = gid - N_CODES;
        const float* row = z + (size_t)r * D_DIM;
        float s = 0.f;
#pragma unroll
        for (int d = 0; d < D_DIM; ++d) { float v = row[d]; s = fmaf(v, v, s); }
        float norm = sqrtf(s);
        norm = fmaxf(norm, 1e-12f);
        float zs = 0.f;
#pragma unroll
        for (int d = 0; d < D_DIM; ++d) {
            float v = row[d] / norm;
            zn[(size_t)r * D_DIM + d] = v;
            zs = fmaf(v, v, zs);
        }
        zz[r] = zs;
    }
}

__global__ __launch_bounds__(NTHREADS, 4)
void vq_main_basic(const float* __restrict__ zn, const float* __restrict__ zz,
                   const float* __restrict__ codebook, const float* __restrict__ cc,
                   float* __restrict__ pminv, int* __restrict__ pmini) {
    __shared__ float cb_lds[C_TILE * CB_PAD];
    __shared__ float zt[R_TILE * D_DIM];
    const int tid = threadIdx.x;
    const int rb = blockIdx.x & 255;
    const int slice = blockIdx.x >> 8;
    const int rg = tid >> 6;
    const int cg = tid & 63;
    const int row_base = rb * R_TILE;
    const int code_base = slice * SLICE_CODES_F;
    const int wrow = row_base + rg * 8;
    {
        float4 v = *reinterpret_cast<const float4*>(zn + (size_t)row_base * D_DIM + tid * 4);
        *reinterpret_cast<float4*>(&zt[tid * 4]) = v;
    }
    float zzr[8];
#pragma unroll
    for (int r = 0; r < 8; ++r) zzr[r] = zz[wrow + r];
    float minv[8]; int mini[8];
#pragma unroll
    for (int r = 0; r < 8; ++r) { minv[r] = 3.4e38f; mini[r] = 0; }
    for (int t = 0; t < N_TILES_F; ++t) {
        const int base = code_base + t * C_TILE;
        __syncthreads();
        {
            const float4* src = reinterpret_cast<const float4*>(codebook + (size_t)(base + tid) * D_DIM);
            float* dstf = &cb_lds[tid * CB_PAD];
#pragma unroll
            for (int k = 0; k < 8; ++k) *reinterpret_cast<float4*>(dstf + k * 4) = src[k];
        }
        __syncthreads();
        float acc[8][4];
#pragma unroll
        for (int r = 0; r < 8; ++r)
#pragma unroll
            for (int j = 0; j < 4; ++j) acc[r][j] = 0.f;
#pragma unroll
        for (int dc = 0; dc < 8; ++dc) {
            float4 cb4[4];
#pragma unroll
            for (int j = 0; j < 4; ++j)
                cb4[j] = *reinterpret_cast<const float4*>(&cb_lds[(cg + 64 * j) * CB_PAD + dc * 4]);
#pragma unroll
            for (int r = 0; r < 8; ++r) {
                const float4 zv = *reinterpret_cast<const float4*>(&zt[(rg * 8 + r) * D_DIM + dc * 4]);
#pragma unroll
                for (int j = 0; j < 4; ++j) {
                    float a = acc[r][j];
                    a = fmaf(zv.x, cb4[j].x, a);
                    a = fmaf(zv.y, cb4[j].y, a);
                    a = fmaf(zv.z, cb4[j].z, a);
                    a = fmaf(zv.w, cb4[j].w, a);
                    acc[r][j] = a;
                }
            }
        }
#pragma unroll
        for (int j = 0; j < 4; ++j) {
            const int code = base + cg + 64 * j;
            const float ccj = cc[code];
#pragma unroll
            for (int r = 0; r < 8; ++r) {
                float tsum = zzr[r] + ccj;
                float dist = fmaf(-2.f, acc[r][j], tsum);
                if (dist < minv[r]) { minv[r] = dist; mini[r] = code; }
            }
        }
    }
#pragma unroll
    for (int r = 0; r < 8; ++r) {
        float v = minv[r]; int i = mini[r];
#pragma unroll
        for (int off = 32; off >= 1; off >>= 1) {
            float ov = __shfl_xor(v, off);
            int   oi = __shfl_xor(i, off);
            if (ov < v || (ov == v && oi < i)) { v = ov; i = oi; }
        }
        minv[r] = v; mini[r] = i;
    }
    if (cg == 0) {
#pragma unroll
        for (int r = 0; r < 8; ++r) {
            pminv[slice * M_ROWS + wrow + r] = minv[r];
            pmini[slice * M_ROWS + wrow + r] = mini[r];
        }
    }
}

__global__ void vq_final_basic(const float* __restrict__ codebook,
                               const float* __restrict__ pminv,
                               const int* __restrict__ pmini,
                               float* __restrict__ zq, float* __restrict__ idx_out) {
    int row = blockIdx.x * NTHREADS + threadIdx.x;
    float bv = pminv[row];
    int   bi = pmini[row];
#pragma unroll
    for (int s = 1; s < NSLICE_F; ++s) {
        float v = pminv[s * M_ROWS + row];
        int   i = pmini[s * M_ROWS + row];
        if (v < bv || (v == bv && i < bi)) { bv = v; bi = i; }
    }
    idx_out[row] = (float)bi;
    const float4* src = reinterpret_cast<const float4*>(codebook + (size_t)bi * D_DIM);
    float4* dst = reinterpret_cast<float4*>(zq + (size_t)row * D_DIM);
#pragma unroll
    for (int k = 0; k < 8; ++k) dst[k] = src[k];
}

// ===========================================================================
static size_t ws_needed(int nslice) {
    return 4ull * (2ull * N_CODES + M_ROWS + 3ull * (size_t)nslice * M_ROWS) +
           4ull * (4 + M_ROWS) +
           2ull * (2ull * N_CODES * D_DIM + 2ull * M_ROWS * D_DIM);
}

template <int NS>
static void launch_mfma_path(const float* z, const float* codebook,
                             float* zn, float* zq_out, float* idx_out,
                             void* d_ws, hipStream_t stream) {
    float* cc    = (float*)d_ws;
    float* cch   = cc + N_CODES;
    float* zz    = cch + N_CODES;
    float* pmax1 = zz + M_ROWS;
    float* pmax2 = pmax1 + (size_t)NS * M_ROWS;
    int*   pidx  = (int*)(pmax2 + (size_t)NS * M_ROWS);
    int*   todo_cnt = pidx + (size_t)NS * M_ROWS;
    int*   todo  = todo_cnt + 4;
    unsigned* chi = (unsigned*)(todo + M_ROWS);
    unsigned* clo = chi + (size_t)N_CODES * D_DIM / 2;
    unsigned* zhi = clo + (size_t)N_CODES * D_DIM / 2;
    unsigned* zlo = zhi + (size_t)M_ROWS * D_DIM / 2;

    // cleanup partials reuse pmax1/pidx (consumed by vq_merge before scan)
    float* cpmin = pmax1;
    int*   cpidx = pidx;

    vq_prep_pack<<<96, NTHREADS, 0, stream>>>(z, codebook, zn, zz, cc, cch,
                                              chi, clo, zhi, zlo, todo_cnt);
    vq_mfma<NS><<<64 * NS, NTHREADS, 0, stream>>>(
        (const unsigned short*)zhi, (const unsigned short*)zlo,
        (const unsigned short*)chi, (const unsigned short*)clo,
        cch, pmax1, pmax2, pidx);
    vq_merge<NS><<<M_ROWS / NTHREADS, NTHREADS, 0, stream>>>(
        codebook, pmax1, pmax2, pidx, zq_out, idx_out, todo_cnt, todo);
    vq_cleanup_scan<<<SCAN_SLOTS * NCHUNK, NTHREADS, 0, stream>>>(
        zn, zz, codebook, cc, todo_cnt, todo, cpmin, cpidx);
    vq_cleanup_final<<<32, NTHREADS, 0, stream>>>(
        codebook, todo_cnt, todo, cpmin, cpidx, zq_out, idx_out);
}

extern "C" void kernel_launch(void* const* d_in, const int* in_sizes, int n_in,
                              void* d_out, int out_size, void* d_ws, size_t ws_size,
                              hipStream_t stream) {
    const float* z        = (const float*)d_in[0];   // [8,1024,32]
    const float* codebook = (const float*)d_in[1];   // [16384,32]

    float* out     = (float*)d_out;
    float* zq_out  = out;                            // 262144 floats
    float* idx_out = out + (size_t)M_ROWS * D_DIM;   // 8192 floats
    float* zn      = zq_out;                         // zn lives in zq region

    if (ws_size >= ws_needed(16)) {
        launch_mfma_path<16>(z, codebook, zn, zq_out, idx_out, d_ws, stream);
    } else {
        // Fallback: proven R3 path (~350 KB ws)
        float* cc    = (float*)d_ws;
        float* zz    = cc + N_CODES;
        float* pminv = zz + M_ROWS;
        int*   pmini = (int*)(pminv + (size_t)NSLICE_F * M_ROWS);

        vq_prep_basic<<<96, NTHREADS, 0, stream>>>(z, codebook, zn, zz, cc);
        vq_main_basic<<<256 * NSLICE_F, NTHREADS, 0, stream>>>(zn, zz, codebook, cc,
                                                               pminv, pmini);
        vq_final_basic<<<M_ROWS / NTHREADS, NTHREADS, 0, stream>>>(codebook, pminv,
                                                                   pmini, zq_out, idx_out);
    }
}